// Round 3
// baseline (410.164 us; speedup 1.0000x reference)
//
#include <hip/hip_runtime.h>
#include <hip/hip_bf16.h>

typedef unsigned short u16;
typedef __bf16  bf16x8 __attribute__((ext_vector_type(8)));
typedef float   f32x4  __attribute__((ext_vector_type(4)));

#define T_TOK 4096   // B*S tokens
#define DIN   4096
#define DOUT  4096
#define NEXP  8
#define ER    128    // E*R
#define KAUG  4224   // DIN + ER
#define SPLIT 8
#define KCH   (DIN / SPLIT)   // 512

// ws layout (bytes)
#define OFF_XB    0u           // bf16 x            33,554,432
#define OFF_WB    33554432u    // bf16 base_w       33,554,432
#define OFF_AB    67108864u    // bf16 lora_A flat   1,048,576
#define OFF_BS2   68157440u    // bf16 2*lora_B^T    1,048,576
#define OFF_U     69206016u    // bf16 U             1,048,576
#define OFF_BBF   70254592u    // fp32 bias             16,384
#define OFF_LG    70270976u    // fp32 logits          131,072
#define OFF_GPART 70402048u    // fp32 partials     16,777,216  -> end 87,179,264

__device__ __forceinline__ void async16(void* lds, const void* g) {
    __builtin_amdgcn_global_load_lds(
        (const __attribute__((address_space(1))) void*)g,
        (__attribute__((address_space(3))) void*)lds,
        16, 0, 0);
}

static __device__ __forceinline__ u16 f2b(float f) {
    __hip_bfloat16 h = __float2bfloat16(f);
    return *(u16*)&h;
}

// ---------------- convert fp32 -> bf16: x and base_w (8 elems/thread)
__global__ __launch_bounds__(256) void convert_big(const float* __restrict__ x,
                                                   const float* __restrict__ w,
                                                   uint4* __restrict__ xb,
                                                   uint4* __restrict__ wb) {
    int gid = blockIdx.x * 256 + threadIdx.x;          // 2 * 2,097,152 threads
    const float4* s = (const float4*)((gid < 2097152) ? x : w);
    uint4* dst      = (gid < 2097152) ? xb : wb;
    int li = gid & 2097151;
    float4 a = s[2 * li], b = s[2 * li + 1];
    uint4 o;
    o.x = (unsigned)f2b(a.x) | ((unsigned)f2b(a.y) << 16);
    o.y = (unsigned)f2b(a.z) | ((unsigned)f2b(a.w) << 16);
    o.z = (unsigned)f2b(b.x) | ((unsigned)f2b(b.y) << 16);
    o.w = (unsigned)f2b(b.z) | ((unsigned)f2b(b.w) << 16);
    dst[li] = o;
}

// ---------------- small packs: lora_A (bf16), 2*lora_B^T (bf16), bias (fp32)
__global__ __launch_bounds__(256) void pack_small(const float* __restrict__ lora_A,
                                                  const float* __restrict__ lora_B,
                                                  const float* __restrict__ base_b,
                                                  u16* __restrict__ ab,
                                                  u16* __restrict__ bs2,
                                                  float* __restrict__ bbf) {
    int idx = blockIdx.x * 256 + threadIdx.x;   // total 1,052,672
    if (idx < 524288) {                          // lora_A flat copy [e*16+r][d]
        ab[idx] = f2b(lora_A[idx]);
    } else if (idx < 1048576) {                  // bs2[o, e*16+r] = 2*lora_B[e,o,r]
        int j = idx - 524288;
        int o = j >> 7, c = j & 127, e = c >> 4, r = c & 15;
        bs2[j] = f2b(lora_B[(e * DOUT + o) * 16 + r] * 2.0f);
    } else if (idx < 1052672) {
        int j = idx - 1048576;
        bbf[j] = base_b[j];
    }
}

// ---------------- fp32 gate logits: Lg[t][e] = dot(x[t], gate_w[e]) ----------------
// one wave per token; exact selection requires fp32 here (bf16 flips near-ties)
__global__ __launch_bounds__(256) void gate_logits(const float* __restrict__ x,
                                                   const float* __restrict__ gw,
                                                   float* __restrict__ Lg) {
    const int w = threadIdx.x >> 6, lid = threadIdx.x & 63;
    const int t = blockIdx.x * 4 + w;
    const float4* xr = (const float4*)(x + (size_t)t * DIN);
    float acc[8] = {0.f, 0.f, 0.f, 0.f, 0.f, 0.f, 0.f, 0.f};
    for (int i = lid; i < DIN / 4; i += 64) {
        float4 xv = xr[i];
#pragma unroll
        for (int e = 0; e < 8; ++e) {
            float4 gv = ((const float4*)(gw + (size_t)e * DIN))[i];
            acc[e] += xv.x * gv.x + xv.y * gv.y + xv.z * gv.z + xv.w * gv.w;
        }
    }
#pragma unroll
    for (int e = 0; e < 8; ++e) {
        float v = acc[e];
        for (int off = 32; off; off >>= 1) v += __shfl_down(v, off, 64);
        if (lid == 0) Lg[t * 8 + e] = v;
    }
}

// ---------------- GEMM1: Gpart[s] += X @ lora_A^T, split-K fp32 partials
// grid (32 mb, 8 split), block 256. Tile 128(M) x 128(N) x 64(K).
__global__ __launch_bounds__(256) void gemm1(const u16* __restrict__ X,
                                             const u16* __restrict__ ab,
                                             float* __restrict__ Gpart) {
    __shared__ __align__(16) u16 As[128 * 64];
    __shared__ __align__(16) u16 Bs[128 * 64];
    const int mb = blockIdx.x, s = blockIdx.y;
    const int w = threadIdx.x >> 6, lid = threadIdx.x & 63;
    const int lrow = lid >> 3;            // row within 8-row chunk
    const int lcolb = (lid & 7) * 16;     // byte offset within 128B row

    f32x4 acc[2][8];
#pragma unroll
    for (int i = 0; i < 2; ++i)
#pragma unroll
        for (int j = 0; j < 8; ++j) acc[i][j] = (f32x4){0.f, 0.f, 0.f, 0.f};

    int k0 = s * KCH;
    for (int kt = 0; kt < KCH / 64; ++kt, k0 += 64) {
#pragma unroll
        for (int q = 0; q < 4; ++q) {
            int c = w * 4 + q;
            int arow = mb * 128 + c * 8 + lrow;
            async16((char*)As + c * 1024,
                    (const char*)X + ((size_t)arow * DIN + k0) * 2 + lcolb);
            async16((char*)Bs + c * 1024,
                    (const char*)ab + ((size_t)(c * 8 + lrow) * DIN + k0) * 2 + lcolb);
        }
        __syncthreads();
#pragma unroll
        for (int ks = 0; ks < 64; ks += 32) {
            bf16x8 a[2], b[8];
#pragma unroll
            for (int i = 0; i < 2; ++i)
                a[i] = *(const bf16x8*)&As[(w * 32 + i * 16 + (lid & 15)) * 64 + ks + (lid >> 4) * 8];
#pragma unroll
            for (int j = 0; j < 8; ++j)
                b[j] = *(const bf16x8*)&Bs[(j * 16 + (lid & 15)) * 64 + ks + (lid >> 4) * 8];
#pragma unroll
            for (int i = 0; i < 2; ++i)
#pragma unroll
                for (int j = 0; j < 8; ++j)
                    acc[i][j] = __builtin_amdgcn_mfma_f32_16x16x32_bf16(a[i], b[j], acc[i][j], 0, 0, 0);
        }
        __syncthreads();
    }
    const int quad = lid >> 4, nl = lid & 15;
#pragma unroll
    for (int i = 0; i < 2; ++i)
#pragma unroll
        for (int j = 0; j < 8; ++j) {
            int n = j * 16 + nl;
            int t = mb * 128 + w * 32 + i * 16 + quad * 4;
            float* dst = Gpart + ((size_t)s * T_TOK + t) * ER + n;
#pragma unroll
            for (int r = 0; r < 4; ++r) dst[(size_t)r * ER] = acc[i][j][r];
        }
}

// ---------------- routing: top-2 softmax (fp32 logits), build U ----------------
__global__ __launch_bounds__(256) void route_u(const float* __restrict__ Gpart,
                                               const float* __restrict__ Lg,
                                               __hip_bfloat16* __restrict__ U) {
    __shared__ float wmap[32][9];
    const int t0 = blockIdx.x * 32;
    const int tid = threadIdx.x;
    if (tid < 32) {
        float l[8];
#pragma unroll
        for (int e = 0; e < 8; ++e) l[e] = Lg[(t0 + tid) * 8 + e];
        int e1 = 0; float b1 = l[0];
#pragma unroll
        for (int e = 1; e < 8; ++e) if (l[e] > b1) { b1 = l[e]; e1 = e; }
        int e2 = -1; float b2 = -3.4e38f;
#pragma unroll
        for (int e = 0; e < 8; ++e) if (e != e1 && l[e] > b2) { b2 = l[e]; e2 = e; }
        float ex = __expf(b2 - b1);
        float inv = 1.f / (1.f + ex);
#pragma unroll
        for (int e = 0; e < 8; ++e) wmap[tid][e] = 0.f;
        wmap[tid][e1] = inv;
        wmap[tid][e2] = ex * inv;
    }
    __syncthreads();
#pragma unroll
    for (int it = 0; it < 16; ++it) {
        int idx = it * 256 + tid;          // 32 tokens * 128 cols
        int tl = idx >> 7, c = idx & 127;
        float sum = 0.f;
        for (int sp = 0; sp < SPLIT; ++sp)
            sum += Gpart[((size_t)sp * T_TOK + t0 + tl) * ER + c];
        U[(size_t)(t0 + tl) * ER + c] = __float2bfloat16(sum * wmap[tl][c >> 4]);
    }
}

// ---------------- GEMM2: out = [X|U] @ [W|Bs2]^T + bias, K=4224, fp32 out ----------------
__global__ __launch_bounds__(256) void gemm2(const u16* __restrict__ X,
                                             const u16* __restrict__ W,
                                             const float* __restrict__ bbf,
                                             const u16* __restrict__ U,
                                             const u16* __restrict__ Bs2,
                                             float* __restrict__ out) {
    __shared__ __align__(16) u16 As[128 * 64];
    __shared__ __align__(16) u16 Bs[128 * 64];
    const int nb = blockIdx.x, mb = blockIdx.y;
    const int w = threadIdx.x >> 6, lid = threadIdx.x & 63;
    const int lrow = lid >> 3, lcolb = (lid & 7) * 16;

    f32x4 acc[4][4];
#pragma unroll
    for (int i = 0; i < 4; ++i)
#pragma unroll
        for (int j = 0; j < 4; ++j) acc[i][j] = (f32x4){0.f, 0.f, 0.f, 0.f};

    const char* aX[4]; const char* aU[4];
    const char* bW[4]; const char* bB[4];
#pragma unroll
    for (int q = 0; q < 4; ++q) {
        int c = w * 4 + q;
        int arow = mb * 128 + c * 8 + lrow;
        aX[q] = (const char*)X + (size_t)arow * (DIN * 2) + lcolb;
        aU[q] = (const char*)U + (size_t)arow * (ER * 2) + lcolb;
        int brow = nb * 128 + c * 8 + lrow;
        bW[q] = (const char*)W + (size_t)brow * (DIN * 2) + lcolb;
        bB[q] = (const char*)Bs2 + (size_t)brow * (ER * 2) + lcolb;
    }

    for (int kt = 0; kt < KAUG / 64; ++kt) {
        int k0 = kt * 64;
        bool basepart = (k0 < DIN);
        size_t off = basepart ? (size_t)k0 * 2 : (size_t)(k0 - DIN) * 2;
#pragma unroll
        for (int q = 0; q < 4; ++q) {
            int c = w * 4 + q;
            async16((char*)As + c * 1024, (basepart ? aX[q] : aU[q]) + off);
            async16((char*)Bs + c * 1024, (basepart ? bW[q] : bB[q]) + off);
        }
        __syncthreads();
        const int wm = w & 1, wn = w >> 1;
#pragma unroll
        for (int ks = 0; ks < 64; ks += 32) {
            bf16x8 a[4], b[4];
#pragma unroll
            for (int i = 0; i < 4; ++i)
                a[i] = *(const bf16x8*)&As[(wm * 64 + i * 16 + (lid & 15)) * 64 + ks + (lid >> 4) * 8];
#pragma unroll
            for (int j = 0; j < 4; ++j)
                b[j] = *(const bf16x8*)&Bs[(wn * 64 + j * 16 + (lid & 15)) * 64 + ks + (lid >> 4) * 8];
#pragma unroll
            for (int i = 0; i < 4; ++i)
#pragma unroll
                for (int j = 0; j < 4; ++j)
                    acc[i][j] = __builtin_amdgcn_mfma_f32_16x16x32_bf16(a[i], b[j], acc[i][j], 0, 0, 0);
        }
        __syncthreads();
    }

    const int wm = w & 1, wn = w >> 1, quad = lid >> 4, nl = lid & 15;
#pragma unroll
    for (int j = 0; j < 4; ++j) {
        int n = nb * 128 + wn * 64 + j * 16 + nl;
        float bz = bbf[n];
#pragma unroll
        for (int i = 0; i < 4; ++i) {
            int m = mb * 128 + wm * 64 + i * 16 + quad * 4;
            float* dst = out + (size_t)m * DOUT + n;
#pragma unroll
            for (int r = 0; r < 4; ++r)
                dst[(size_t)r * DOUT] = acc[i][j][r] + bz;
        }
    }
}

extern "C" void kernel_launch(void* const* d_in, const int* in_sizes, int n_in,
                              void* d_out, int out_size, void* d_ws, size_t ws_size,
                              hipStream_t stream) {
    const float* x      = (const float*)d_in[0];
    const float* gate_w = (const float*)d_in[1];
    const float* base_w = (const float*)d_in[2];
    const float* base_b = (const float*)d_in[3];
    const float* lora_A = (const float*)d_in[4];
    const float* lora_B = (const float*)d_in[5];
    float* out = (float*)d_out;

    char* ws = (char*)d_ws;
    u16*   xb    = (u16*)(ws + OFF_XB);
    u16*   wb    = (u16*)(ws + OFF_WB);
    u16*   ab    = (u16*)(ws + OFF_AB);
    u16*   bs2   = (u16*)(ws + OFF_BS2);
    u16*   U     = (u16*)(ws + OFF_U);
    float* bbf   = (float*)(ws + OFF_BBF);
    float* Lg    = (float*)(ws + OFF_LG);
    float* Gpart = (float*)(ws + OFF_GPART);

    convert_big<<<16384, 256, 0, stream>>>(x, base_w, (uint4*)xb, (uint4*)wb);
    pack_small<<<4112, 256, 0, stream>>>(lora_A, lora_B, base_b, ab, bs2, bbf);
    gate_logits<<<T_TOK / 4, 256, 0, stream>>>(x, gate_w, Lg);
    gemm1<<<dim3(32, SPLIT), 256, 0, stream>>>(xb, ab, Gpart);
    route_u<<<T_TOK / 32, 256, 0, stream>>>(Gpart, Lg, (__hip_bfloat16*)U);
    gemm2<<<dim3(32, 32), 256, 0, stream>>>(xb, wb, bbf, U, bs2, out);
}

// Round 4
// 362.014 us; speedup vs baseline: 1.1330x; 1.1330x over previous
//
#include <hip/hip_runtime.h>
#include <hip/hip_bf16.h>

typedef unsigned short u16;
typedef __bf16  bf16x8 __attribute__((ext_vector_type(8)));
typedef float   f32x4  __attribute__((ext_vector_type(4)));

#define T_TOK 4096   // B*S tokens
#define DIN   4096
#define DOUT  4096
#define NEXP  8
#define ER    128    // E*R
#define SPLIT 8
#define KCH   (DIN / SPLIT)   // 512

// ws layout (bytes)
#define OFF_XB    0u           // bf16 x            33,554,432
#define OFF_WB    33554432u    // bf16 base_w       33,554,432
#define OFF_AB    67108864u    // bf16 lora_A flat   1,048,576
#define OFF_BS2   68157440u    // bf16 2*lora_B^T    1,048,576
#define OFF_U     69206016u    // bf16 U             1,048,576
#define OFF_BBF   70254592u    // fp32 bias             16,384
#define OFF_LG    70270976u    // fp32 logits          131,072
#define OFF_GPART 70402048u    // fp32 partials     16,777,216  -> end 87,179,264

__device__ __forceinline__ void async16(void* lds, const void* g) {
    __builtin_amdgcn_global_load_lds(
        (const __attribute__((address_space(1))) void*)g,
        (__attribute__((address_space(3))) void*)lds,
        16, 0, 0);
}

static __device__ __forceinline__ u16 f2b(float f) {
    __hip_bfloat16 h = __float2bfloat16(f);
    return *(u16*)&h;
}

// XOR-swizzled LDS read: slot (row, g') holds global column-group g'^ (row&7).
// Bank-group = g'*4 -> varies with row after swizzle -> conflict-free.
__device__ __forceinline__ bf16x8 lds8(const u16* base, int row, int grp) {
    return *(const bf16x8*)((const char*)base + row * 128 + (((grp ^ row) & 7) * 16));
}

// ---------------- convert fp32 -> bf16: x and base_w (8 elems/thread)
__global__ __launch_bounds__(256) void convert_big(const float* __restrict__ x,
                                                   const float* __restrict__ w,
                                                   uint4* __restrict__ xb,
                                                   uint4* __restrict__ wb) {
    int gid = blockIdx.x * 256 + threadIdx.x;          // 2 * 2,097,152 threads
    const float4* s = (const float4*)((gid < 2097152) ? x : w);
    uint4* dst      = (gid < 2097152) ? xb : wb;
    int li = gid & 2097151;
    float4 a = s[2 * li], b = s[2 * li + 1];
    uint4 o;
    o.x = (unsigned)f2b(a.x) | ((unsigned)f2b(a.y) << 16);
    o.y = (unsigned)f2b(a.z) | ((unsigned)f2b(a.w) << 16);
    o.z = (unsigned)f2b(b.x) | ((unsigned)f2b(b.y) << 16);
    o.w = (unsigned)f2b(b.z) | ((unsigned)f2b(b.w) << 16);
    dst[li] = o;
}

// ---------------- small packs: lora_A (bf16), 2*lora_B^T (bf16), bias (fp32)
__global__ __launch_bounds__(256) void pack_small(const float* __restrict__ lora_A,
                                                  const float* __restrict__ lora_B,
                                                  const float* __restrict__ base_b,
                                                  u16* __restrict__ ab,
                                                  u16* __restrict__ bs2,
                                                  float* __restrict__ bbf) {
    int idx = blockIdx.x * 256 + threadIdx.x;   // total 1,052,672
    if (idx < 524288) {                          // lora_A flat copy [e*16+r][d]
        ab[idx] = f2b(lora_A[idx]);
    } else if (idx < 1048576) {                  // bs2[o, e*16+r] = 2*lora_B[e,o,r]
        int j = idx - 524288;
        int o = j >> 7, c = j & 127, e = c >> 4, r = c & 15;
        bs2[j] = f2b(lora_B[(e * DOUT + o) * 16 + r] * 2.0f);
    } else if (idx < 1052672) {
        int j = idx - 1048576;
        bbf[j] = base_b[j];
    }
}

// ---------------- fp32 gate logits: 4 tokens per wave (gate_w load reuse) ----------------
__global__ __launch_bounds__(256) void gate_logits(const float* __restrict__ x,
                                                   const float* __restrict__ gw,
                                                   float* __restrict__ Lg) {
    const int w = threadIdx.x >> 6, lid = threadIdx.x & 63;
    const int t0 = (blockIdx.x * 4 + w) * 4;
    float acc[4][8];
#pragma unroll
    for (int j = 0; j < 4; ++j)
#pragma unroll
        for (int e = 0; e < 8; ++e) acc[j][e] = 0.f;
    for (int i = lid; i < DIN / 4; i += 64) {
        float4 gv[8];
#pragma unroll
        for (int e = 0; e < 8; ++e)
            gv[e] = ((const float4*)(gw + (size_t)e * DIN))[i];
#pragma unroll
        for (int j = 0; j < 4; ++j) {
            float4 xv = ((const float4*)(x + (size_t)(t0 + j) * DIN))[i];
#pragma unroll
            for (int e = 0; e < 8; ++e)
                acc[j][e] += xv.x * gv[e].x + xv.y * gv[e].y + xv.z * gv[e].z + xv.w * gv[e].w;
        }
    }
#pragma unroll
    for (int j = 0; j < 4; ++j)
#pragma unroll
        for (int e = 0; e < 8; ++e) {
            float v = acc[j][e];
            for (int off = 32; off; off >>= 1) v += __shfl_down(v, off, 64);
            if (lid == 0) Lg[(t0 + j) * 8 + e] = v;
        }
}

// ---------------- GEMM1: Gpart[s] = X @ lora_A^T, split-K fp32 partials
// grid (32 mb, 8 split), block 256. Tile 128(M) x 128(N) x 64(K).
__global__ __launch_bounds__(256) void gemm1(const u16* __restrict__ X,
                                             const u16* __restrict__ ab,
                                             float* __restrict__ Gpart) {
    __shared__ __align__(16) u16 As[128 * 64];
    __shared__ __align__(16) u16 Bs[128 * 64];
    const int mb = blockIdx.x, s = blockIdx.y;
    const int w = threadIdx.x >> 6, lid = threadIdx.x & 63;
    const int lrow = lid >> 3;                    // row within 8-row chunk
    const int lcolb = ((lid & 7) ^ lrow) * 16;    // swizzled source column group

    f32x4 acc[2][8];
#pragma unroll
    for (int i = 0; i < 2; ++i)
#pragma unroll
        for (int j = 0; j < 8; ++j) acc[i][j] = (f32x4){0.f, 0.f, 0.f, 0.f};

    int k0 = s * KCH;
    for (int kt = 0; kt < KCH / 64; ++kt, k0 += 64) {
#pragma unroll
        for (int q = 0; q < 4; ++q) {
            int c = w * 4 + q;
            int arow = mb * 128 + c * 8 + lrow;
            async16((char*)As + c * 1024,
                    (const char*)X + ((size_t)arow * DIN + k0) * 2 + lcolb);
            async16((char*)Bs + c * 1024,
                    (const char*)ab + ((size_t)(c * 8 + lrow) * DIN + k0) * 2 + lcolb);
        }
        __syncthreads();
        const int quad = lid >> 4, half = lid & 15;
#pragma unroll
        for (int ks8 = 0; ks8 < 8; ks8 += 4) {
            bf16x8 a[2], b[8];
#pragma unroll
            for (int i = 0; i < 2; ++i)
                a[i] = lds8(As, w * 32 + i * 16 + half, ks8 + quad);
#pragma unroll
            for (int j = 0; j < 8; ++j)
                b[j] = lds8(Bs, j * 16 + half, ks8 + quad);
#pragma unroll
            for (int i = 0; i < 2; ++i)
#pragma unroll
                for (int j = 0; j < 8; ++j)
                    acc[i][j] = __builtin_amdgcn_mfma_f32_16x16x32_bf16(a[i], b[j], acc[i][j], 0, 0, 0);
        }
        __syncthreads();
    }
    const int quad = lid >> 4, nl = lid & 15;
#pragma unroll
    for (int i = 0; i < 2; ++i)
#pragma unroll
        for (int j = 0; j < 8; ++j) {
            int n = j * 16 + nl;
            int t = mb * 128 + w * 32 + i * 16 + quad * 4;
            float* dst = Gpart + ((size_t)s * T_TOK + t) * ER + n;
#pragma unroll
            for (int r = 0; r < 4; ++r) dst[(size_t)r * ER] = acc[i][j][r];
        }
}

// ---------------- routing: top-2 softmax (fp32 logits), build U (vectorized) ----------------
__global__ __launch_bounds__(256) void route_u(const float* __restrict__ Gpart,
                                               const float* __restrict__ Lg,
                                               u16* __restrict__ U) {
    __shared__ float wmap[16][9];
    const int t0 = blockIdx.x * 16;
    const int tid = threadIdx.x;
    if (tid < 16) {
        float l[8];
#pragma unroll
        for (int e = 0; e < 8; ++e) l[e] = Lg[(t0 + tid) * 8 + e];
        int e1 = 0; float b1 = l[0];
#pragma unroll
        for (int e = 1; e < 8; ++e) if (l[e] > b1) { b1 = l[e]; e1 = e; }
        int e2 = -1; float b2 = -3.4e38f;
#pragma unroll
        for (int e = 0; e < 8; ++e) if (e != e1 && l[e] > b2) { b2 = l[e]; e2 = e; }
        float ex = __expf(b2 - b1);
        float inv = 1.f / (1.f + ex);
#pragma unroll
        for (int e = 0; e < 8; ++e) wmap[tid][e] = 0.f;
        wmap[tid][e1] = inv;
        wmap[tid][e2] = ex * inv;
    }
    __syncthreads();
#pragma unroll
    for (int it = 0; it < 2; ++it) {
        int idx = it * 256 + tid;          // 16 tokens * 32 float4-cols
        int tl = idx >> 5, c4 = idx & 31;
        float4 s = {0.f, 0.f, 0.f, 0.f};
        for (int sp = 0; sp < SPLIT; ++sp) {
            float4 g = ((const float4*)(Gpart + ((size_t)sp * T_TOK + t0 + tl) * ER))[c4];
            s.x += g.x; s.y += g.y; s.z += g.z; s.w += g.w;
        }
        float wv = wmap[tl][c4 >> 2];
        ushort4 o = { f2b(s.x * wv), f2b(s.y * wv), f2b(s.z * wv), f2b(s.w * wv) };
        ((ushort4*)(U + (size_t)(t0 + tl) * ER))[c4] = o;
    }
}

// ---------------- GEMM2: out = [X|U] @ [W|Bs2]^T + bias, fp32 out ----------------
// Branchless main K-loop (64 iters over DIN) + 2-iter LoRA tail.
__global__ __launch_bounds__(256) void gemm2(const u16* __restrict__ X,
                                             const u16* __restrict__ W,
                                             const float* __restrict__ bbf,
                                             const u16* __restrict__ U,
                                             const u16* __restrict__ Bs2,
                                             float* __restrict__ out) {
    __shared__ __align__(16) u16 As[128 * 64];
    __shared__ __align__(16) u16 Bs[128 * 64];
    const int nb = blockIdx.x, mb = blockIdx.y;
    const int w = threadIdx.x >> 6, lid = threadIdx.x & 63;
    const int lrow = lid >> 3;
    const int lcolb = ((lid & 7) ^ lrow) * 16;    // swizzled source column group

    f32x4 acc[4][4];
#pragma unroll
    for (int i = 0; i < 4; ++i)
#pragma unroll
        for (int j = 0; j < 4; ++j) acc[i][j] = (f32x4){0.f, 0.f, 0.f, 0.f};

    const char* pa[4]; const char* pb[4];
#pragma unroll
    for (int q = 0; q < 4; ++q) {
        int c = w * 4 + q;
        pa[q] = (const char*)X + (size_t)(mb * 128 + c * 8 + lrow) * (DIN * 2) + lcolb;
        pb[q] = (const char*)W + (size_t)(nb * 128 + c * 8 + lrow) * (DIN * 2) + lcolb;
    }

    const int quad = lid >> 4, half = lid & 15;
    const int wm = w & 1, wn = w >> 1;

#define MFMA_TILE                                                              \
    _Pragma("unroll")                                                          \
    for (int ks8 = 0; ks8 < 8; ks8 += 4) {                                     \
        bf16x8 a[4], b[4];                                                     \
        _Pragma("unroll")                                                      \
        for (int i = 0; i < 4; ++i)                                            \
            a[i] = lds8(As, wm * 64 + i * 16 + half, ks8 + quad);              \
        _Pragma("unroll")                                                      \
        for (int j = 0; j < 4; ++j)                                            \
            b[j] = lds8(Bs, wn * 64 + j * 16 + half, ks8 + quad);              \
        _Pragma("unroll")                                                      \
        for (int i = 0; i < 4; ++i)                                            \
            _Pragma("unroll")                                                  \
            for (int j = 0; j < 4; ++j)                                        \
                acc[i][j] = __builtin_amdgcn_mfma_f32_16x16x32_bf16(           \
                    a[i], b[j], acc[i][j], 0, 0, 0);                           \
    }

    for (int kt = 0; kt < 64; ++kt) {
#pragma unroll
        for (int q = 0; q < 4; ++q) {
            int c = w * 4 + q;
            async16((char*)As + c * 1024, pa[q]);
            async16((char*)Bs + c * 1024, pb[q]);
            pa[q] += 128;
            pb[q] += 128;
        }
        __syncthreads();
        MFMA_TILE
        __syncthreads();
    }
    // LoRA tail: K = 128 over U / Bs2
    for (int kt = 0; kt < 2; ++kt) {
#pragma unroll
        for (int q = 0; q < 4; ++q) {
            int c = w * 4 + q;
            async16((char*)As + c * 1024,
                    (const char*)U + (size_t)(mb * 128 + c * 8 + lrow) * (ER * 2) + kt * 128 + lcolb);
            async16((char*)Bs + c * 1024,
                    (const char*)Bs2 + (size_t)(nb * 128 + c * 8 + lrow) * (ER * 2) + kt * 128 + lcolb);
        }
        __syncthreads();
        MFMA_TILE
        __syncthreads();
    }

    const int nl = lid & 15;
#pragma unroll
    for (int j = 0; j < 4; ++j) {
        int n = nb * 128 + wn * 64 + j * 16 + nl;
        float bz = bbf[n];
#pragma unroll
        for (int i = 0; i < 4; ++i) {
            int m = mb * 128 + wm * 64 + i * 16 + quad * 4;
            float* dst = out + (size_t)m * DOUT + n;
#pragma unroll
            for (int r = 0; r < 4; ++r)
                dst[(size_t)r * DOUT] = acc[i][j][r] + bz;
        }
    }
}

extern "C" void kernel_launch(void* const* d_in, const int* in_sizes, int n_in,
                              void* d_out, int out_size, void* d_ws, size_t ws_size,
                              hipStream_t stream) {
    const float* x      = (const float*)d_in[0];
    const float* gate_w = (const float*)d_in[1];
    const float* base_w = (const float*)d_in[2];
    const float* base_b = (const float*)d_in[3];
    const float* lora_A = (const float*)d_in[4];
    const float* lora_B = (const float*)d_in[5];
    float* out = (float*)d_out;

    char* ws = (char*)d_ws;
    u16*   xb    = (u16*)(ws + OFF_XB);
    u16*   wb    = (u16*)(ws + OFF_WB);
    u16*   ab    = (u16*)(ws + OFF_AB);
    u16*   bs2   = (u16*)(ws + OFF_BS2);
    u16*   U     = (u16*)(ws + OFF_U);
    float* bbf   = (float*)(ws + OFF_BBF);
    float* Lg    = (float*)(ws + OFF_LG);
    float* Gpart = (float*)(ws + OFF_GPART);

    convert_big<<<16384, 256, 0, stream>>>(x, base_w, (uint4*)xb, (uint4*)wb);
    pack_small<<<4112, 256, 0, stream>>>(lora_A, lora_B, base_b, ab, bs2, bbf);
    gate_logits<<<T_TOK / 16, 256, 0, stream>>>(x, gate_w, Lg);
    gemm1<<<dim3(32, SPLIT), 256, 0, stream>>>(xb, ab, Gpart);
    route_u<<<T_TOK / 16, 256, 0, stream>>>(Gpart, Lg, U);
    gemm2<<<dim3(32, 32), 256, 0, stream>>>(xb, wb, bbf, U, bs2, out);
}